// Round 1
// baseline (375.536 us; speedup 1.0000x reference)
//
#include <hip/hip_runtime.h>
#include <math.h>

#define Bv 64
#define Jv 20000
#define Dv 32
#define Hv 64
#define Wv 4
#define AEv 16
#define GHv 24
#define EHv 128
#define Lv 32

// ---------------- precompute per-j terms ----------------
// pre1[j][k] = sum_d F[j][d]*h_W1[1+d][k] + h_b1[k]        (k<64)
// gb[j][c]   = sum_a AE[atse[j]][a]*g_W1[32+a][c] + g_b1[c] (c<24)
__global__ __launch_bounds__(256) void pe_precompute(
    const float* __restrict__ fe, const int* __restrict__ atse_idx,
    const float* __restrict__ ae, const float* __restrict__ hW1,
    const float* __restrict__ hb1, const float* __restrict__ gW1,
    const float* __restrict__ gb1, float* __restrict__ pre1,
    float* __restrict__ gbuf) {
  __shared__ __align__(16) float s_hW1[33 * 64];
  __shared__ __align__(16) float s_gW1[16 * 24];
  __shared__ __align__(16) float s_hb1[64];
  __shared__ __align__(16) float s_gb1[24];
  int tid = threadIdx.x;
  for (int i = tid; i < 33 * 64; i += 256) s_hW1[i] = hW1[i];
  for (int i = tid; i < 16 * 24; i += 256) s_gW1[i] = gW1[32 * 24 + i];
  if (tid < 64) s_hb1[tid] = hb1[tid];
  if (tid < 24) s_gb1[tid] = gb1[tid];
  __syncthreads();
  int j = blockIdx.x * 256 + tid;
  if (j >= Jv) return;

  float F[32];
  const float4* fv = (const float4*)(fe + (size_t)j * 32);
#pragma unroll
  for (int q = 0; q < 8; ++q) {
    float4 v = fv[q];
    F[q * 4] = v.x; F[q * 4 + 1] = v.y; F[q * 4 + 2] = v.z; F[q * 4 + 3] = v.w;
  }
  int idx = atse_idx[j];
  float A[16];
  const float4* av = (const float4*)(ae + (size_t)idx * 16);
#pragma unroll
  for (int q = 0; q < 4; ++q) {
    float4 v = av[q];
    A[q * 4] = v.x; A[q * 4 + 1] = v.y; A[q * 4 + 2] = v.z; A[q * 4 + 3] = v.w;
  }

  float4* outp = (float4*)(pre1 + (size_t)j * 64);
#pragma unroll 4
  for (int k4 = 0; k4 < 16; ++k4) {
    float4 acc = ((const float4*)s_hb1)[k4];
#pragma unroll
    for (int d = 0; d < 32; ++d) {
      float4 w = *((const float4*)(s_hW1 + (1 + d) * 64) + k4);
      acc.x = fmaf(F[d], w.x, acc.x);
      acc.y = fmaf(F[d], w.y, acc.y);
      acc.z = fmaf(F[d], w.z, acc.z);
      acc.w = fmaf(F[d], w.w, acc.w);
    }
    outp[k4] = acc;
  }

  float4* outg = (float4*)(gbuf + (size_t)j * 24);
#pragma unroll
  for (int c4 = 0; c4 < 6; ++c4) {
    float4 acc = ((const float4*)s_gb1)[c4];
#pragma unroll
    for (int a = 0; a < 16; ++a) {
      float4 w = *((const float4*)(s_gW1 + a * 24) + c4);
      acc.x = fmaf(A[a], w.x, acc.x);
      acc.y = fmaf(A[a], w.y, acc.y);
      acc.z = fmaf(A[a], w.z, acc.z);
      acc.w = fmaf(A[a], w.w, acc.w);
    }
    outg[c4] = acc;
  }
}

// ---------------- main per-(b,j) kernel ----------------
__global__ __launch_bounds__(256, 2) void pe_main(
    const float* __restrict__ x, const int* __restrict__ mask,
    const float* __restrict__ hW1, const float* __restrict__ hln1g,
    const float* __restrict__ hln1b, const float* __restrict__ hW2,
    const float* __restrict__ hb2, const float* __restrict__ hln2g,
    const float* __restrict__ hln2b, const float* __restrict__ gW1,
    const float* __restrict__ gW2, const float* __restrict__ gb2,
    const float* __restrict__ pre1, const float* __restrict__ gbuf,
    float* __restrict__ acc_g, float* __restrict__ se_g) {
  __shared__ __align__(16) float s_W2[64 * 32];
  __shared__ __align__(16) float s_gW1[32 * 24];
  __shared__ __align__(16) float s_gW2[24 * 4];
  __shared__ float s_w0[64], s_l1g[64], s_l1b[64];
  __shared__ float s_b2[32], s_l2g[32], s_l2b[32];
  __shared__ float s_gb2[4];
  __shared__ float s_e[256 * 5];   // stride 5: conflict-free
  __shared__ float s_h[256 * 33];  // stride 33: conflict-free

  int tid = threadIdx.x;
  int b = blockIdx.x;
  int jbase = blockIdx.y * 256;

  for (int i = tid; i < 64 * 32; i += 256) s_W2[i] = hW2[i];
  for (int i = tid; i < 32 * 24; i += 256) s_gW1[i] = gW1[i];
  if (tid < 96) s_gW2[tid] = gW2[tid];
  if (tid < 64) { s_w0[tid] = hW1[tid]; s_l1g[tid] = hln1g[tid]; s_l1b[tid] = hln1b[tid]; }
  if (tid < 32) { s_b2[tid] = hb2[tid]; s_l2g[tid] = hln2g[tid]; s_l2b[tid] = hln2b[tid]; }
  if (tid < 4) s_gb2[tid] = gb2[tid];
  __syncthreads();

  int j = jbase + tid;
  bool active = false;
  if (j < Jv) active = (mask[(size_t)b * Jv + j] != 0);

  float e0 = 0.f, e1 = 0.f, e2 = 0.f, e3 = 0.f;
  float ho[32];

  if (active) {
    float xv = x[(size_t)b * Jv + j];
    float t[64];
    const float4* pv = (const float4*)(pre1 + (size_t)j * 64);
#pragma unroll
    for (int k4 = 0; k4 < 16; ++k4) {
      float4 v = pv[k4];
      t[4 * k4]     = fmaf(xv, s_w0[4 * k4],     v.x);
      t[4 * k4 + 1] = fmaf(xv, s_w0[4 * k4 + 1], v.y);
      t[4 * k4 + 2] = fmaf(xv, s_w0[4 * k4 + 2], v.z);
      t[4 * k4 + 3] = fmaf(xv, s_w0[4 * k4 + 3], v.w);
    }
    // LN1 (64, affine) + relu
    float s = 0.f;
#pragma unroll
    for (int k = 0; k < 64; ++k) s += t[k];
    float mu = s * (1.0f / 64.0f);
    float vv = 0.f;
#pragma unroll
    for (int k = 0; k < 64; ++k) { float d = t[k] - mu; vv = fmaf(d, d, vv); }
    float rs = rsqrtf(vv * (1.0f / 64.0f) + 1e-5f);
#pragma unroll
    for (int k = 0; k < 64; ++k)
      t[k] = fmaxf(fmaf((t[k] - mu) * rs, s_l1g[k], s_l1b[k]), 0.0f);

    // h2 = h @ W2 + b2
    float h2[32];
#pragma unroll
    for (int d = 0; d < 32; ++d) h2[d] = s_b2[d];
#pragma unroll 8
    for (int k = 0; k < 64; ++k) {
      float hk = t[k];
      const float4* row = (const float4*)(s_W2 + k * 32);
#pragma unroll
      for (int q = 0; q < 8; ++q) {
        float4 w = row[q];
        h2[4 * q]     = fmaf(hk, w.x, h2[4 * q]);
        h2[4 * q + 1] = fmaf(hk, w.y, h2[4 * q + 1]);
        h2[4 * q + 2] = fmaf(hk, w.z, h2[4 * q + 2]);
        h2[4 * q + 3] = fmaf(hk, w.w, h2[4 * q + 3]);
      }
    }
    // LN2 (32, affine) + relu
    s = 0.f;
#pragma unroll
    for (int d = 0; d < 32; ++d) s += h2[d];
    mu = s * (1.0f / 32.0f);
    vv = 0.f;
#pragma unroll
    for (int d = 0; d < 32; ++d) { float dd = h2[d] - mu; vv = fmaf(dd, dd, vv); }
    rs = rsqrtf(vv * (1.0f / 32.0f) + 1e-5f);
#pragma unroll
    for (int d = 0; d < 32; ++d)
      ho[d] = fmaxf(fmaf((h2[d] - mu) * rs, s_l2g[d], s_l2b[d]), 0.0f);

    // gate: g1 = ho @ gW1[:32] + gb[j]  (gb includes ae part + bias)
    float g1[24];
    const float4* gbv = (const float4*)(gbuf + (size_t)j * 24);
#pragma unroll
    for (int c4 = 0; c4 < 6; ++c4) {
      float4 v = gbv[c4];
      g1[4 * c4] = v.x; g1[4 * c4 + 1] = v.y; g1[4 * c4 + 2] = v.z; g1[4 * c4 + 3] = v.w;
    }
#pragma unroll 8
    for (int i = 0; i < 32; ++i) {
      float hv = ho[i];
      const float4* row = (const float4*)(s_gW1 + i * 24);
#pragma unroll
      for (int c4 = 0; c4 < 6; ++c4) {
        float4 w = row[c4];
        g1[4 * c4]     = fmaf(hv, w.x, g1[4 * c4]);
        g1[4 * c4 + 1] = fmaf(hv, w.y, g1[4 * c4 + 1]);
        g1[4 * c4 + 2] = fmaf(hv, w.z, g1[4 * c4 + 2]);
        g1[4 * c4 + 3] = fmaf(hv, w.w, g1[4 * c4 + 3]);
      }
    }
    float r0 = s_gb2[0], r1 = s_gb2[1], r2 = s_gb2[2], r3 = s_gb2[3];
#pragma unroll
    for (int c = 0; c < 24; ++c) {
      float gv = fmaxf(g1[c], 0.0f);
      float4 w = ((const float4*)s_gW2)[c];
      r0 = fmaf(gv, w.x, r0);
      r1 = fmaf(gv, w.y, r1);
      r2 = fmaf(gv, w.z, r2);
      r3 = fmaf(gv, w.w, r3);
    }
    // clip and shifted exp (logits <= 10 so shift by 10 is safe; masked -> 0)
    r0 = fminf(fmaxf(r0, -10.f), 10.f);
    r1 = fminf(fmaxf(r1, -10.f), 10.f);
    r2 = fminf(fmaxf(r2, -10.f), 10.f);
    r3 = fminf(fmaxf(r3, -10.f), 10.f);
    e0 = __expf(r0 - 10.f);
    e1 = __expf(r1 - 10.f);
    e2 = __expf(r2 - 10.f);
    e3 = __expf(r3 - 10.f);
  } else {
#pragma unroll
    for (int d = 0; d < 32; ++d) ho[d] = 0.0f;
  }

  s_e[tid * 5 + 0] = e0;
  s_e[tid * 5 + 1] = e1;
  s_e[tid * 5 + 2] = e2;
  s_e[tid * 5 + 3] = e3;
#pragma unroll
  for (int d = 0; d < 32; ++d) s_h[tid * 33 + d] = ho[d];
  __syncthreads();

  // block reduce: acc[w][d] = sum_t e[t][w]*h[t][d]; se[w] = sum_t e[t][w]
  if (tid < 128) {
    int w = tid >> 5, d = tid & 31;
    float a = 0.f;
#pragma unroll 8
    for (int i = 0; i < 256; ++i) a = fmaf(s_e[i * 5 + w], s_h[i * 33 + d], a);
    atomicAdd(&acc_g[(b * 4 + w) * 32 + d], a);
  } else if (tid < 132) {
    int w = tid - 128;
    float ssum = 0.f;
#pragma unroll 8
    for (int i = 0; i < 256; ++i) ssum += s_e[i * 5 + w];
    atomicAdd(&se_g[b * 4 + w], ssum);
  }
}

// ---------------- per-b tail: normalize, c-layer, encoder MLP ----------------
__global__ __launch_bounds__(64) void pe_tail(
    const float* __restrict__ acc_g, const float* __restrict__ se_g,
    const float* __restrict__ cW, const float* __restrict__ cb,
    const float* __restrict__ clng, const float* __restrict__ clnb,
    const float* __restrict__ eW1, const float* __restrict__ eb1,
    const float* __restrict__ eW2, const float* __restrict__ eb2,
    float* __restrict__ out) {
  int b = blockIdx.x;
  int lane = threadIdx.x;  // 64 threads = 1 wave
  __shared__ float s_hs[128], s_comb[32], s_e1[128];

  float se0 = se_g[b * 4 + 0];
  bool empty = !(se0 > 0.0f);
  float inv[4];
#pragma unroll
  for (int w = 0; w < 4; ++w) {
    float sw = se_g[b * 4 + w];
    inv[w] = empty ? 0.0f : 1.0f / sw;
  }
  s_hs[lane] = acc_g[b * 128 + lane] * inv[lane >> 5];
  s_hs[lane + 64] = acc_g[b * 128 + lane + 64] * inv[(lane + 64) >> 5];
  __syncthreads();

  // combined = relu(LN_affine(hs @ cW + cb)); zero if empty
  if (lane < 32) {
    float cp = cb[lane];
#pragma unroll 8
    for (int i = 0; i < 128; ++i) cp = fmaf(s_hs[i], cW[i * 32 + lane], cp);
    float ssum = cp;
#pragma unroll
    for (int off = 16; off > 0; off >>= 1) ssum += __shfl_xor(ssum, off, 32);
    float mu = ssum * (1.0f / 32.0f);
    float dd = cp - mu;
    float sq = dd * dd;
#pragma unroll
    for (int off = 16; off > 0; off >>= 1) sq += __shfl_xor(sq, off, 32);
    float rs = rsqrtf(sq * (1.0f / 32.0f) + 1e-5f);
    float comb = fmaxf(fmaf(dd * rs, clng[lane], clnb[lane]), 0.0f);
    if (empty) comb = 0.0f;
    s_comb[lane] = comb;
  }
  __syncthreads();

  // e1 = relu(LN(comb @ eW1 + eb1))  (no affine), 128 wide
  float v0 = eb1[lane], v1 = eb1[lane + 64];
#pragma unroll
  for (int i = 0; i < 32; ++i) {
    float c = s_comb[i];
    v0 = fmaf(c, eW1[i * 128 + lane], v0);
    v1 = fmaf(c, eW1[i * 128 + lane + 64], v1);
  }
  float ssum = v0 + v1;
#pragma unroll
  for (int off = 32; off > 0; off >>= 1) ssum += __shfl_xor(ssum, off, 64);
  float mu = ssum * (1.0f / 128.0f);
  float d0 = v0 - mu, d1 = v1 - mu;
  float sq = fmaf(d0, d0, d1 * d1);
#pragma unroll
  for (int off = 32; off > 0; off >>= 1) sq += __shfl_xor(sq, off, 64);
  float rs = rsqrtf(sq * (1.0f / 128.0f) + 1e-5f);
  s_e1[lane] = fmaxf(d0 * rs, 0.0f);
  s_e1[lane + 64] = fmaxf(d1 * rs, 0.0f);
  __syncthreads();

  // mu_logvar = relu(LN(e1 @ eW2 + eb2)) (no affine), 64 wide
  float v = eb2[lane];
#pragma unroll 8
  for (int i = 0; i < 128; ++i) v = fmaf(s_e1[i], eW2[i * 64 + lane], v);
  ssum = v;
#pragma unroll
  for (int off = 32; off > 0; off >>= 1) ssum += __shfl_xor(ssum, off, 64);
  mu = ssum * (1.0f / 64.0f);
  float dv = v - mu;
  sq = dv * dv;
#pragma unroll
  for (int off = 32; off > 0; off >>= 1) sq += __shfl_xor(sq, off, 64);
  rs = rsqrtf(sq * (1.0f / 64.0f) + 1e-5f);
  float o = fmaxf(dv * rs, 0.0f);
  if (lane < 32)
    out[b * 32 + lane] = o;                       // mu
  else
    out[Bv * 32 + b * 32 + (lane - 32)] = o;      // logvar
}

extern "C" void kernel_launch(void* const* d_in, const int* in_sizes, int n_in,
                              void* d_out, int out_size, void* d_ws, size_t ws_size,
                              hipStream_t stream) {
  const float* x    = (const float*)d_in[0];
  const int* mask   = (const int*)d_in[1];
  const int* atse   = (const int*)d_in[2];
  const float* fe   = (const float*)d_in[3];
  const float* ae   = (const float*)d_in[4];
  const float* hW1  = (const float*)d_in[5];
  const float* hb1  = (const float*)d_in[6];
  const float* hl1g = (const float*)d_in[7];
  const float* hl1b = (const float*)d_in[8];
  const float* hW2  = (const float*)d_in[9];
  const float* hb2  = (const float*)d_in[10];
  const float* hl2g = (const float*)d_in[11];
  const float* hl2b = (const float*)d_in[12];
  const float* gW1  = (const float*)d_in[13];
  const float* gb1  = (const float*)d_in[14];
  const float* gW2  = (const float*)d_in[15];
  const float* gb2  = (const float*)d_in[16];
  const float* cW   = (const float*)d_in[17];
  const float* cb   = (const float*)d_in[18];
  const float* clng = (const float*)d_in[19];
  const float* clnb = (const float*)d_in[20];
  const float* eW1  = (const float*)d_in[21];
  const float* eb1  = (const float*)d_in[22];
  const float* eW2  = (const float*)d_in[23];
  const float* eb2  = (const float*)d_in[24];
  float* out = (float*)d_out;

  float* ws = (float*)d_ws;
  float* pre1 = ws;                                  // J*64
  float* gbuf = ws + (size_t)Jv * 64;                // J*24
  float* accg = gbuf + (size_t)Jv * 24;              // B*128
  float* seg  = accg + Bv * 128;                     // B*4

  hipMemsetAsync(accg, 0, (Bv * 128 + Bv * 4) * sizeof(float), stream);

  int jblocks = (Jv + 255) / 256;  // 79
  pe_precompute<<<dim3(jblocks), dim3(256), 0, stream>>>(
      fe, atse, ae, hW1, hb1, gW1, gb1, pre1, gbuf);
  pe_main<<<dim3(Bv, jblocks), dim3(256), 0, stream>>>(
      x, mask, hW1, hl1g, hl1b, hW2, hb2, hl2g, hl2b, gW1, gW2, gb2,
      pre1, gbuf, accg, seg);
  pe_tail<<<dim3(Bv), dim3(64), 0, stream>>>(
      accg, seg, cW, cb, clng, clnb, eW1, eb1, eW2, eb2, out);
}

// Round 2
// 336.070 us; speedup vs baseline: 1.1174x; 1.1174x over previous
//
#include <hip/hip_runtime.h>
#include <math.h>

#define Bv 64
#define Jv 20000
#define NSEG 8
#define SEGLEN 2500

// ---------------- per-segment mask counts ----------------
__global__ __launch_bounds__(256) void pe_count(const int* __restrict__ mask,
                                                int* __restrict__ segtot) {
  int b = blockIdx.x, s = blockIdx.y, tid = threadIdx.x;
  int c0 = s * SEGLEN;
  int local = 0;
  for (int q = c0 + tid; q < c0 + SEGLEN; q += 256)
    local += (mask[(size_t)b * Jv + q] != 0);
#pragma unroll
  for (int off = 32; off > 0; off >>= 1) local += __shfl_xor(local, off, 64);
  __shared__ int sw[4];
  if ((tid & 63) == 0) sw[tid >> 6] = local;
  __syncthreads();
  if (tid == 0) segtot[b * NSEG + s] = sw[0] + sw[1] + sw[2] + sw[3];
}

// ---------------- ordered compaction of active j per b ----------------
__global__ __launch_bounds__(256) void pe_compact(const int* __restrict__ mask,
                                                  const int* __restrict__ segtot,
                                                  int* __restrict__ jlist,
                                                  int* __restrict__ count) {
  int b = blockIdx.x, s = blockIdx.y, tid = threadIdx.x;
  int base = 0;
  for (int t = 0; t < s; ++t) base += segtot[b * NSEG + t];
  int c0 = s * SEGLEN;
  __shared__ int sw[4];
  int lane = tid & 63, wid = tid >> 6;
  for (int c = 0; c < 10; ++c) {
    int j = c0 + c * 256 + tid;
    bool a = (j < c0 + SEGLEN) && (mask[(size_t)b * Jv + j] != 0);
    unsigned long long bal = __ballot(a);
    int pre = __popcll(bal & ((1ull << lane) - 1ull));
    if (lane == 0) sw[wid] = __popcll(bal);
    __syncthreads();
    int wbase = base;
    for (int t = 0; t < wid; ++t) wbase += sw[t];
    if (a) jlist[(size_t)b * Jv + wbase + pre] = j;
    int tot = sw[0] + sw[1] + sw[2] + sw[3];
    __syncthreads();
    base += tot;
  }
  if (s == NSEG - 1 && tid == 0) count[b] = base;
}

// ---------------- precompute per-j terms ----------------
// pre1[j][k] = sum_d F[j][d]*h_W1[1+d][k] + h_b1[k]         (k<64)
// exj[j]     = {sum_k p, sum_k p^2, sum_k w0[k]*p[k], 0}
// gbuf[j][c] = sum_a AE[atse[j]][a]*g_W1[32+a][c] + g_b1[c] (c<24)
// sc[0..1]   = {sum_k w0[k], sum_k w0[k]^2}
__global__ __launch_bounds__(256) void pe_precompute(
    const float* __restrict__ fe, const int* __restrict__ atse_idx,
    const float* __restrict__ ae, const float* __restrict__ hW1,
    const float* __restrict__ hb1, const float* __restrict__ gW1,
    const float* __restrict__ gb1, float* __restrict__ pre1,
    float* __restrict__ exj, float* __restrict__ gbuf,
    float* __restrict__ sc) {
  __shared__ __align__(16) float s_hW1[33 * 64];
  __shared__ __align__(16) float s_gW1[16 * 24];
  __shared__ __align__(16) float s_hb1[64];
  __shared__ __align__(16) float s_gb1[24];
  int tid = threadIdx.x;
  for (int i = tid; i < 33 * 64; i += 256) s_hW1[i] = hW1[i];
  for (int i = tid; i < 16 * 24; i += 256) s_gW1[i] = gW1[32 * 24 + i];
  if (tid < 64) s_hb1[tid] = hb1[tid];
  if (tid < 24) s_gb1[tid] = gb1[tid];
  __syncthreads();

  if (blockIdx.x == 0 && tid == 0) {
    float sw = 0.f, qw = 0.f;
    for (int k = 0; k < 64; ++k) {
      float w = s_hW1[k];
      sw += w;
      qw = fmaf(w, w, qw);
    }
    sc[0] = sw;
    sc[1] = qw;
  }

  int j = blockIdx.x * 256 + tid;
  if (j >= Jv) return;

  float F[32];
  const float4* fv = (const float4*)(fe + (size_t)j * 32);
#pragma unroll
  for (int q = 0; q < 8; ++q) {
    float4 v = fv[q];
    F[q * 4] = v.x; F[q * 4 + 1] = v.y; F[q * 4 + 2] = v.z; F[q * 4 + 3] = v.w;
  }
  int idx = atse_idx[j];
  float A[16];
  const float4* av = (const float4*)(ae + (size_t)idx * 16);
#pragma unroll
  for (int q = 0; q < 4; ++q) {
    float4 v = av[q];
    A[q * 4] = v.x; A[q * 4 + 1] = v.y; A[q * 4 + 2] = v.z; A[q * 4 + 3] = v.w;
  }

  float4* outp = (float4*)(pre1 + (size_t)j * 64);
  float sp = 0.f, qp = 0.f, dwp = 0.f;
#pragma unroll 4
  for (int k4 = 0; k4 < 16; ++k4) {
    float4 acc = ((const float4*)s_hb1)[k4];
#pragma unroll
    for (int d = 0; d < 32; ++d) {
      float4 w = *((const float4*)(s_hW1 + (1 + d) * 64) + k4);
      acc.x = fmaf(F[d], w.x, acc.x);
      acc.y = fmaf(F[d], w.y, acc.y);
      acc.z = fmaf(F[d], w.z, acc.z);
      acc.w = fmaf(F[d], w.w, acc.w);
    }
    outp[k4] = acc;
    sp += acc.x + acc.y + acc.z + acc.w;
    qp = fmaf(acc.x, acc.x, qp); qp = fmaf(acc.y, acc.y, qp);
    qp = fmaf(acc.z, acc.z, qp); qp = fmaf(acc.w, acc.w, qp);
    float4 w0c = ((const float4*)s_hW1)[k4];
    dwp = fmaf(acc.x, w0c.x, dwp); dwp = fmaf(acc.y, w0c.y, dwp);
    dwp = fmaf(acc.z, w0c.z, dwp); dwp = fmaf(acc.w, w0c.w, dwp);
  }
  ((float4*)exj)[j] = make_float4(sp, qp, dwp, 0.f);

  float4* outg = (float4*)(gbuf + (size_t)j * 24);
#pragma unroll
  for (int c4 = 0; c4 < 6; ++c4) {
    float4 acc = ((const float4*)s_gb1)[c4];
#pragma unroll
    for (int a = 0; a < 16; ++a) {
      float4 w = *((const float4*)(s_gW1 + a * 24) + c4);
      acc.x = fmaf(A[a], w.x, acc.x);
      acc.y = fmaf(A[a], w.y, acc.y);
      acc.z = fmaf(A[a], w.z, acc.z);
      acc.w = fmaf(A[a], w.w, acc.w);
    }
    outg[c4] = acc;
  }
}

// ---------------- main per-active-(b,j) kernel ----------------
__global__ __launch_bounds__(256, 4) void pe_main(
    const float* __restrict__ x, const int* __restrict__ jlist,
    const int* __restrict__ count, const float* __restrict__ hW1,
    const float* __restrict__ hln1g, const float* __restrict__ hln1b,
    const float* __restrict__ hW2, const float* __restrict__ hb2,
    const float* __restrict__ hln2g, const float* __restrict__ hln2b,
    const float* __restrict__ gW1, const float* __restrict__ gW2,
    const float* __restrict__ gb2, const float* __restrict__ pre1,
    const float* __restrict__ exj, const float* __restrict__ gbuf,
    const float* __restrict__ sc, float* __restrict__ acc_g,
    float* __restrict__ se_g) {
  int b = blockIdx.x;
  int cnt = count[b];
  int jbase = blockIdx.y * 256;
  if (jbase >= cnt) return;

  __shared__ __align__(16) float s_W2[64 * 32];
  __shared__ __align__(16) float s_gW1[32 * 24];
  __shared__ __align__(16) float s_gW2[24 * 4];
  __shared__ __align__(16) float s_w0[64];
  __shared__ __align__(16) float s_l1g[64];
  __shared__ __align__(16) float s_l1b[64];
  __shared__ __align__(16) float s_b2[32];
  __shared__ __align__(16) float s_l2g[32];
  __shared__ __align__(16) float s_l2b[32];
  __shared__ float s_gb2[4];
  __shared__ float s_e[256 * 5];   // stride 5: 2-way max (free)
  __shared__ float s_h[256 * 17];  // stride 17: 2-way max (free)
  __shared__ float s_part[256];
  __shared__ float s_parte[16];

  int tid = threadIdx.x;
  for (int i = tid; i < 64 * 32; i += 256) s_W2[i] = hW2[i];
  for (int i = tid; i < 32 * 24; i += 256) s_gW1[i] = gW1[i];
  if (tid < 96) s_gW2[tid] = gW2[tid];
  if (tid < 64) { s_w0[tid] = hW1[tid]; s_l1g[tid] = hln1g[tid]; s_l1b[tid] = hln1b[tid]; }
  if (tid < 32) { s_b2[tid] = hb2[tid]; s_l2g[tid] = hln2g[tid]; s_l2b[tid] = hln2b[tid]; }
  if (tid < 4) s_gb2[tid] = gb2[tid];
  __syncthreads();

  int idx = jbase + tid;
  bool valid = idx < cnt;
  int j = 0;
  float xv = 0.f;
  if (valid) {
    j = jlist[(size_t)b * Jv + idx];
    xv = x[(size_t)b * Jv + j];
  }
  float4 ex = ((const float4*)exj)[j];
  float Sw0 = sc[0], Qw0 = sc[1];
  // closed-form LN1 stats: t_k = xv*w0[k] + p[k]
  float mu1 = fmaf(xv, Sw0, ex.x) * (1.0f / 64.0f);
  float Et2 = (xv * xv * Qw0 + 2.0f * xv * ex.z + ex.y) * (1.0f / 64.0f);
  float rs1 = rsqrtf(fmaxf(Et2 - mu1 * mu1, 0.0f) + 1e-5f);

  float h2[32];
#pragma unroll
  for (int q = 0; q < 8; ++q) {
    float4 bb = ((const float4*)s_b2)[q];
    h2[4 * q] = bb.x; h2[4 * q + 1] = bb.y; h2[4 * q + 2] = bb.z; h2[4 * q + 3] = bb.w;
  }
  const float4* pv = (const float4*)pre1 + (size_t)j * 16;
#pragma unroll 4
  for (int k4 = 0; k4 < 16; ++k4) {
    float4 p  = pv[k4];
    float4 w0 = ((const float4*)s_w0)[k4];
    float4 lg = ((const float4*)s_l1g)[k4];
    float4 lb = ((const float4*)s_l1b)[k4];
    float tv[4], av[4];
    tv[0] = fmaf(xv, w0.x, p.x); tv[1] = fmaf(xv, w0.y, p.y);
    tv[2] = fmaf(xv, w0.z, p.z); tv[3] = fmaf(xv, w0.w, p.w);
    av[0] = fmaxf(fmaf((tv[0] - mu1) * rs1, lg.x, lb.x), 0.f);
    av[1] = fmaxf(fmaf((tv[1] - mu1) * rs1, lg.y, lb.y), 0.f);
    av[2] = fmaxf(fmaf((tv[2] - mu1) * rs1, lg.z, lb.z), 0.f);
    av[3] = fmaxf(fmaf((tv[3] - mu1) * rs1, lg.w, lb.w), 0.f);
#pragma unroll
    for (int u = 0; u < 4; ++u) {
      float a = av[u];
      const float4* row = (const float4*)(s_W2 + (k4 * 4 + u) * 32);
#pragma unroll
      for (int q = 0; q < 8; ++q) {
        float4 w = row[q];
        h2[4 * q]     = fmaf(a, w.x, h2[4 * q]);
        h2[4 * q + 1] = fmaf(a, w.y, h2[4 * q + 1]);
        h2[4 * q + 2] = fmaf(a, w.z, h2[4 * q + 2]);
        h2[4 * q + 3] = fmaf(a, w.w, h2[4 * q + 3]);
      }
    }
  }
  // LN2 + relu, in place
  {
    float s = 0.f;
#pragma unroll
    for (int d = 0; d < 32; ++d) s += h2[d];
    float mu2 = s * (1.0f / 32.0f);
    float vv = 0.f;
#pragma unroll
    for (int d = 0; d < 32; ++d) { float dd = h2[d] - mu2; vv = fmaf(dd, dd, vv); }
    float rs2 = rsqrtf(vv * (1.0f / 32.0f) + 1e-5f);
#pragma unroll
    for (int d = 0; d < 32; ++d)
      h2[d] = fmaxf(fmaf((h2[d] - mu2) * rs2, s_l2g[d], s_l2b[d]), 0.f);
  }
  // gate
  float e0, e1, e2, e3;
  {
    float g1[24];
    const float4* gbv = (const float4*)(gbuf + (size_t)j * 24);
#pragma unroll
    for (int c4 = 0; c4 < 6; ++c4) {
      float4 v = gbv[c4];
      g1[4 * c4] = v.x; g1[4 * c4 + 1] = v.y; g1[4 * c4 + 2] = v.z; g1[4 * c4 + 3] = v.w;
    }
#pragma unroll 8
    for (int i = 0; i < 32; ++i) {
      float hv = h2[i];
      const float4* row = (const float4*)(s_gW1 + i * 24);
#pragma unroll
      for (int c4 = 0; c4 < 6; ++c4) {
        float4 w = row[c4];
        g1[4 * c4]     = fmaf(hv, w.x, g1[4 * c4]);
        g1[4 * c4 + 1] = fmaf(hv, w.y, g1[4 * c4 + 1]);
        g1[4 * c4 + 2] = fmaf(hv, w.z, g1[4 * c4 + 2]);
        g1[4 * c4 + 3] = fmaf(hv, w.w, g1[4 * c4 + 3]);
      }
    }
    float r0 = s_gb2[0], r1 = s_gb2[1], r2 = s_gb2[2], r3 = s_gb2[3];
#pragma unroll
    for (int c = 0; c < 24; ++c) {
      float gv = fmaxf(g1[c], 0.0f);
      float4 w = ((const float4*)s_gW2)[c];
      r0 = fmaf(gv, w.x, r0);
      r1 = fmaf(gv, w.y, r1);
      r2 = fmaf(gv, w.z, r2);
      r3 = fmaf(gv, w.w, r3);
    }
    // clip; exp shifted by the clip ceiling (10) -> masked contribute exactly 0
    r0 = fminf(fmaxf(r0, -10.f), 10.f);
    r1 = fminf(fmaxf(r1, -10.f), 10.f);
    r2 = fminf(fmaxf(r2, -10.f), 10.f);
    r3 = fminf(fmaxf(r3, -10.f), 10.f);
    e0 = valid ? __expf(r0 - 10.f) : 0.f;
    e1 = valid ? __expf(r1 - 10.f) : 0.f;
    e2 = valid ? __expf(r2 - 10.f) : 0.f;
    e3 = valid ? __expf(r3 - 10.f) : 0.f;
  }

  s_e[tid * 5 + 0] = e0;
  s_e[tid * 5 + 1] = e1;
  s_e[tid * 5 + 2] = e2;
  s_e[tid * 5 + 3] = e3;
  // ---- chunk 0: d in [0,16) ----
#pragma unroll
  for (int dd = 0; dd < 16; ++dd) s_h[tid * 17 + dd] = h2[dd];
  __syncthreads();
  int seg = tid >> 6, p = tid & 63, w = p >> 4, dd0 = p & 15;
  {
    float a = 0.f, ae = 0.f;
    int i0 = seg * 64;
#pragma unroll 8
    for (int i = i0; i < i0 + 64; ++i) {
      float ev = s_e[i * 5 + w];
      a = fmaf(ev, s_h[i * 17 + dd0], a);
      ae += ev;
    }
    s_part[p * 4 + seg] = a;
    if (dd0 == 0) s_parte[w * 4 + seg] = ae;
  }
  __syncthreads();
  if (tid < 64) {
    float tot = s_part[tid * 4 + 0] + s_part[tid * 4 + 1] +
                s_part[tid * 4 + 2] + s_part[tid * 4 + 3];
    int ww = tid >> 4, d = tid & 15;
    atomicAdd(&acc_g[(b * 4 + ww) * 32 + d], tot);
  }
  if (tid < 4) {
    float tot = s_parte[tid * 4 + 0] + s_parte[tid * 4 + 1] +
                s_parte[tid * 4 + 2] + s_parte[tid * 4 + 3];
    atomicAdd(&se_g[b * 4 + tid], tot);
  }
  // ---- chunk 1: d in [16,32) ----
#pragma unroll
  for (int dd = 0; dd < 16; ++dd) s_h[tid * 17 + dd] = h2[16 + dd];
  __syncthreads();
  {
    float a = 0.f;
    int i0 = seg * 64;
#pragma unroll 8
    for (int i = i0; i < i0 + 64; ++i)
      a = fmaf(s_e[i * 5 + w], s_h[i * 17 + dd0], a);
    s_part[p * 4 + seg] = a;
  }
  __syncthreads();
  if (tid < 64) {
    float tot = s_part[tid * 4 + 0] + s_part[tid * 4 + 1] +
                s_part[tid * 4 + 2] + s_part[tid * 4 + 3];
    int ww = tid >> 4, d = tid & 15;
    atomicAdd(&acc_g[(b * 4 + ww) * 32 + 16 + d], tot);
  }
}

// ---------------- per-b tail: normalize, c-layer, encoder MLP ----------------
__global__ __launch_bounds__(64) void pe_tail(
    const float* __restrict__ acc_g, const float* __restrict__ se_g,
    const float* __restrict__ cW, const float* __restrict__ cb,
    const float* __restrict__ clng, const float* __restrict__ clnb,
    const float* __restrict__ eW1, const float* __restrict__ eb1,
    const float* __restrict__ eW2, const float* __restrict__ eb2,
    float* __restrict__ out) {
  int b = blockIdx.x;
  int lane = threadIdx.x;  // 64 threads = 1 wave
  __shared__ float s_hs[128], s_comb[32], s_e1[128];

  float se0 = se_g[b * 4 + 0];
  bool empty = !(se0 > 0.0f);
  float inv[4];
#pragma unroll
  for (int w = 0; w < 4; ++w) {
    float sw = se_g[b * 4 + w];
    inv[w] = empty ? 0.0f : 1.0f / sw;
  }
  s_hs[lane] = acc_g[b * 128 + lane] * inv[lane >> 5];
  s_hs[lane + 64] = acc_g[b * 128 + lane + 64] * inv[(lane + 64) >> 5];
  __syncthreads();

  if (lane < 32) {
    float cp = cb[lane];
#pragma unroll 8
    for (int i = 0; i < 128; ++i) cp = fmaf(s_hs[i], cW[i * 32 + lane], cp);
    float ssum = cp;
#pragma unroll
    for (int off = 16; off > 0; off >>= 1) ssum += __shfl_xor(ssum, off, 32);
    float mu = ssum * (1.0f / 32.0f);
    float dd = cp - mu;
    float sq = dd * dd;
#pragma unroll
    for (int off = 16; off > 0; off >>= 1) sq += __shfl_xor(sq, off, 32);
    float rs = rsqrtf(sq * (1.0f / 32.0f) + 1e-5f);
    float comb = fmaxf(fmaf(dd * rs, clng[lane], clnb[lane]), 0.0f);
    if (empty) comb = 0.0f;
    s_comb[lane] = comb;
  }
  __syncthreads();

  float v0 = eb1[lane], v1 = eb1[lane + 64];
#pragma unroll
  for (int i = 0; i < 32; ++i) {
    float c = s_comb[i];
    v0 = fmaf(c, eW1[i * 128 + lane], v0);
    v1 = fmaf(c, eW1[i * 128 + lane + 64], v1);
  }
  float ssum = v0 + v1;
#pragma unroll
  for (int off = 32; off > 0; off >>= 1) ssum += __shfl_xor(ssum, off, 64);
  float mu = ssum * (1.0f / 128.0f);
  float d0 = v0 - mu, d1 = v1 - mu;
  float sq = fmaf(d0, d0, d1 * d1);
#pragma unroll
  for (int off = 32; off > 0; off >>= 1) sq += __shfl_xor(sq, off, 64);
  float rs = rsqrtf(sq * (1.0f / 128.0f) + 1e-5f);
  s_e1[lane] = fmaxf(d0 * rs, 0.0f);
  s_e1[lane + 64] = fmaxf(d1 * rs, 0.0f);
  __syncthreads();

  float v = eb2[lane];
#pragma unroll 8
  for (int i = 0; i < 128; ++i) v = fmaf(s_e1[i], eW2[i * 64 + lane], v);
  ssum = v;
#pragma unroll
  for (int off = 32; off > 0; off >>= 1) ssum += __shfl_xor(ssum, off, 64);
  mu = ssum * (1.0f / 64.0f);
  float dv = v - mu;
  sq = dv * dv;
#pragma unroll
  for (int off = 32; off > 0; off >>= 1) sq += __shfl_xor(sq, off, 64);
  rs = rsqrtf(sq * (1.0f / 64.0f) + 1e-5f);
  float o = fmaxf(dv * rs, 0.0f);
  if (lane < 32)
    out[b * 32 + lane] = o;                       // mu
  else
    out[Bv * 32 + b * 32 + (lane - 32)] = o;      // logvar
}

extern "C" void kernel_launch(void* const* d_in, const int* in_sizes, int n_in,
                              void* d_out, int out_size, void* d_ws, size_t ws_size,
                              hipStream_t stream) {
  const float* x    = (const float*)d_in[0];
  const int* mask   = (const int*)d_in[1];
  const int* atse   = (const int*)d_in[2];
  const float* fe   = (const float*)d_in[3];
  const float* ae   = (const float*)d_in[4];
  const float* hW1  = (const float*)d_in[5];
  const float* hb1  = (const float*)d_in[6];
  const float* hl1g = (const float*)d_in[7];
  const float* hl1b = (const float*)d_in[8];
  const float* hW2  = (const float*)d_in[9];
  const float* hb2  = (const float*)d_in[10];
  const float* hl2g = (const float*)d_in[11];
  const float* hl2b = (const float*)d_in[12];
  const float* gW1  = (const float*)d_in[13];
  const float* gb1  = (const float*)d_in[14];
  const float* gW2  = (const float*)d_in[15];
  const float* gb2  = (const float*)d_in[16];
  const float* cW   = (const float*)d_in[17];
  const float* cb   = (const float*)d_in[18];
  const float* clng = (const float*)d_in[19];
  const float* clnb = (const float*)d_in[20];
  const float* eW1  = (const float*)d_in[21];
  const float* eb1  = (const float*)d_in[22];
  const float* eW2  = (const float*)d_in[23];
  const float* eb2  = (const float*)d_in[24];
  float* out = (float*)d_out;

  float* ws = (float*)d_ws;
  float* pre1 = ws;                               // 1,280,000 f
  float* exj  = pre1 + (size_t)Jv * 64;           //    80,000 f
  float* gbuf = exj + (size_t)Jv * 4;             //   480,000 f
  float* accg = gbuf + (size_t)Jv * 24;           //     8,192 f
  float* seg  = accg + Bv * 128;                  //       256 f
  float* sc   = seg + Bv * 4;                     //         4 f
  int* segtot = (int*)(sc + 4);                   //       512 i
  int* count  = segtot + Bv * NSEG;               //        64 i
  int* jlist  = count + Bv;                       // 1,280,000 i

  hipMemsetAsync(accg, 0, (Bv * 128 + Bv * 4) * sizeof(float), stream);

  pe_count<<<dim3(Bv, NSEG), dim3(256), 0, stream>>>(mask, segtot);
  pe_compact<<<dim3(Bv, NSEG), dim3(256), 0, stream>>>(mask, segtot, jlist, count);

  int jblocks = (Jv + 255) / 256;  // 79 (worst case; blocks beyond count exit)
  pe_precompute<<<dim3(jblocks), dim3(256), 0, stream>>>(
      fe, atse, ae, hW1, hb1, gW1, gb1, pre1, exj, gbuf, sc);
  pe_main<<<dim3(Bv, jblocks), dim3(256), 0, stream>>>(
      x, jlist, count, hW1, hl1g, hl1b, hW2, hb2, hl2g, hl2b, gW1, gW2, gb2,
      pre1, exj, gbuf, sc, accg, seg);
  pe_tail<<<dim3(Bv), dim3(64), 0, stream>>>(
      accg, seg, cW, cb, clng, clnb, eW1, eb1, eW2, eb2, out);
}